// Round 1
// baseline (422.430 us; speedup 1.0000x reference)
//
#include <hip/hip_runtime.h>
#include <hip/hip_bf16.h>
#include <math.h>

// Problem constants (from the reference)
#define NATOMS   2000000
#define NALT     8
#define BDIM     8
#define CDIM     4
#define RDIM     512
#define OUT_HALF (BDIM * CDIM * RDIM * NALT)   // 131072 floats per output tensor

// One thread per atom. desc: (N,4) int32 [at, b, c, r]; mask: (N,8) int32;
// facc: (N,8) f32; props: (500,8) f32; out: [finalMC | finalSC] concatenated.
__global__ void __launch_bounds__(256) vdw_scatter_kernel(
    const int*   __restrict__ desc,
    const int*   __restrict__ mask,
    const float* __restrict__ facc,
    const float* __restrict__ props,
    const float* __restrict__ weight,
    float*       __restrict__ out,
    int n)
{
    const int i = blockIdx.x * blockDim.x + threadIdx.x;
    if (i >= n) return;

    const float scale = (1.0f - tanhf(weight[0])) * 0.3f;

    // 16B vector load of the 4 description ints
    const int4 d = reinterpret_cast<const int4*>(desc)[i];
    const int at = d.x, b = d.y, c = d.z, r = d.w;

    if (r == -1) return;  // padding

    const float vdw = props[at * 8 + 0];
    const bool  bb  = (at >= 0) & (at <= 3);

    float* base = out + (bb ? 0 : OUT_HALF)
                      + (((b * CDIM + c) * RDIM + r) * NALT);

    const float4 f0 = reinterpret_cast<const float4*>(facc)[i * 2 + 0];
    const float4 f1 = reinterpret_cast<const float4*>(facc)[i * 2 + 1];
    const int4   m0 = reinterpret_cast<const int4*>(mask)[i * 2 + 0];
    const int4   m1 = reinterpret_cast<const int4*>(mask)[i * 2 + 1];

    const float vs = vdw * scale;

    float v;
    v = m0.x ? vs * fmaxf(f0.x, 0.0f) : 0.0f; if (v != 0.0f) atomicAdd(base + 0, v);
    v = m0.y ? vs * fmaxf(f0.y, 0.0f) : 0.0f; if (v != 0.0f) atomicAdd(base + 1, v);
    v = m0.z ? vs * fmaxf(f0.z, 0.0f) : 0.0f; if (v != 0.0f) atomicAdd(base + 2, v);
    v = m0.w ? vs * fmaxf(f0.w, 0.0f) : 0.0f; if (v != 0.0f) atomicAdd(base + 3, v);
    v = m1.x ? vs * fmaxf(f1.x, 0.0f) : 0.0f; if (v != 0.0f) atomicAdd(base + 4, v);
    v = m1.y ? vs * fmaxf(f1.y, 0.0f) : 0.0f; if (v != 0.0f) atomicAdd(base + 5, v);
    v = m1.z ? vs * fmaxf(f1.z, 0.0f) : 0.0f; if (v != 0.0f) atomicAdd(base + 6, v);
    v = m1.w ? vs * fmaxf(f1.w, 0.0f) : 0.0f; if (v != 0.0f) atomicAdd(base + 7, v);
}

extern "C" void kernel_launch(void* const* d_in, const int* in_sizes, int n_in,
                              void* d_out, int out_size, void* d_ws, size_t ws_size,
                              hipStream_t stream)
{
    // Input order per setup_inputs():
    // 0: coords (N,3) f32          -- unused
    // 1: atom_description (N,4) int
    // 2: alternativeMask (N,8) int (bool -> int per harness convention)
    // 3: facc (N,8) f32
    // 4: atom_Properties (500,8) f32
    // 5: weight (1,) f32
    const int*   desc   = (const int*)d_in[1];
    const int*   mask   = (const int*)d_in[2];
    const float* facc   = (const float*)d_in[3];
    const float* props  = (const float*)d_in[4];
    const float* weight = (const float*)d_in[5];
    float*       out    = (float*)d_out;

    const int n = in_sizes[1] / 4;  // N atoms (desc has 4 ints per atom)

    // d_out is poisoned (0xAA) before timing and never re-poisoned between
    // replays: zero it every call.
    hipMemsetAsync(d_out, 0, (size_t)out_size * sizeof(float), stream);

    const int block = 256;
    const int grid  = (n + block - 1) / block;
    vdw_scatter_kernel<<<grid, block, 0, stream>>>(desc, mask, facc, props,
                                                   weight, out, n);
}